// Round 2
// baseline (3842.890 us; speedup 1.0000x reference)
//
#include <hip/hip_runtime.h>
#include <math.h>
#include <cstdio>

// ---------------------------------------------------------------------------
// FNO2d forward, MI355X. Channel-last f32 activations [B,H,W,C], B=4.
// Spectral conv via partial DFT (only m modes kept). Lift, bilinear
// upsampling, and the fc1/gelu/fc2 head are fused into the layer kernels.
// ---------------------------------------------------------------------------

__device__ __forceinline__ float gelu_f(float v) {
    return 0.5f * v * (1.0f + erff(v * 0.70710678118654752f));
}

// tw[t] = (cos(2*pi*t/256), sin(2*pi*t/256)); (k*x*step)&255 indexes
// e^{2*pi*i*k*x/N} for N in {64,128,256}, step = 256/N.
__global__ void init_tw_kernel(float2* tw) {
    int t = threadIdx.x;
    tw[t] = make_float2(cospif(t * (1.0f / 128.0f)), sinpif(t * (1.0f / 128.0f)));
}

// [Co,Ci] -> dst[i*Co + o]
__global__ void transpose_mat_kernel(const float* __restrict__ src,
                                     float* __restrict__ dst, int Co, int Ci) {
    int idx = blockIdx.x * blockDim.x + threadIdx.x;
    if (idx >= Ci * Co) return;
    int o = idx % Co; int i = idx / Co;
    dst[idx] = src[(size_t)o * Ci + i];
}

// Stage A: Fx[(by*M2+kx)*Ctot + Coff + c] = sum_x u(b,y,x,c) * e^{-2pi i kx x/W}
// SRC: 0 = direct [.,H,W,C]; 1 = lift from x[.,H,W,6]; 2 = bilinear-up from
// half-res S[.,Hs,Ws,C] (half-pixel centers, edge clamp).
template <int M2, int SRC>
__global__ void dftx_kernel(const float* __restrict__ U, int C, int Coff, int Ctot,
                            int H, int W, int Hs, int Ws,
                            const float* __restrict__ liftW, const float* __restrict__ liftB,
                            int stepW, const float2* __restrict__ tw,
                            float2* __restrict__ Fx) {
    __shared__ float twc[256], tws[256];
    for (int t = threadIdx.x; t < 256; t += blockDim.x) {
        float2 v = tw[t]; twc[t] = v.x; tws[t] = v.y;
    }
    __syncthreads();
    int by = blockIdx.x;                       // b*H + y
    int c = blockIdx.y * 64 + threadIdx.x;
    if (c >= C) return;

    const float* rowD = nullptr;
    const float* Sa = nullptr; const float* Sb = nullptr;
    float wy = 0.f, bc = 0.f;
    float w6[6] = {0, 0, 0, 0, 0, 0};
    if constexpr (SRC == 0) {
        rowD = U + (size_t)by * W * C + c;
    } else if constexpr (SRC == 1) {
        bc = liftB[c];
#pragma unroll
        for (int j = 0; j < 6; j++) w6[j] = liftW[c * 6 + j];
    } else {
        int b = by / H, y = by % H;
        float fy = 0.5f * y - 0.25f;
        int y0 = (int)floorf(fy); wy = fy - y0;
        int ya = y0 < 0 ? 0 : y0;
        int yb = (y0 + 1 > Hs - 1) ? Hs - 1 : y0 + 1;
        Sa = U + ((size_t)(b * Hs + ya) * Ws) * C + c;
        Sb = U + ((size_t)(b * Hs + yb) * Ws) * C + c;
    }

    float ar[M2], ai[M2];
#pragma unroll
    for (int k = 0; k < M2; k++) { ar[k] = 0.f; ai[k] = 0.f; }
    for (int x = 0; x < W; x++) {
        float u;
        if constexpr (SRC == 0) {
            u = rowD[(size_t)x * C];
        } else if constexpr (SRC == 1) {
            const float* xp = U + ((size_t)by * W + x) * 6;
            u = bc;
#pragma unroll
            for (int j = 0; j < 6; j++) u += w6[j] * xp[j];
        } else {
            float fx = 0.5f * x - 0.25f;
            int x0 = (int)floorf(fx); float wx = fx - x0;
            int xa = x0 < 0 ? 0 : x0;
            int xb2 = (x0 + 1 > Ws - 1) ? Ws - 1 : x0 + 1;
            float va = Sa[(size_t)xa * C] * (1.f - wx) + Sa[(size_t)xb2 * C] * wx;
            float vb = Sb[(size_t)xa * C] * (1.f - wx) + Sb[(size_t)xb2 * C] * wx;
            u = va * (1.f - wy) + vb * wy;
        }
        int tb = (x * stepW) & 255;
        int t = 0;
#pragma unroll
        for (int k = 0; k < M2; k++) {
            ar[k] += u * twc[t];
            ai[k] -= u * tws[t];
            t = (t + tb) & 255;
        }
    }
    float2* o = Fx + ((size_t)by * M2) * Ctot + Coff + c;
#pragma unroll
    for (int k = 0; k < M2; k++) o[(size_t)k * Ctot] = make_float2(ar[k], ai[k]);
}

// Stage B: XF[((b*2m1+kyi)*m2+kx)*Ct + c] = sum_y Fx[...] * e^{-2pi i ky y/H}
__global__ void dfty_kernel(const float2* __restrict__ Fx, int H, int m1, int m2, int Ct,
                            int stepH, const float2* __restrict__ tw,
                            float2* __restrict__ XF, int N) {
    __shared__ float twc[256], tws[256];
    for (int t = threadIdx.x; t < 256; t += blockDim.x) {
        float2 v = tw[t]; twc[t] = v.x; tws[t] = v.y;
    }
    __syncthreads();
    int idx = blockIdx.x * blockDim.x + threadIdx.x;
    if (idx >= N) return;
    int c = idx % Ct; int r = idx / Ct;
    int kx = r % m2;  r /= m2;
    int kyi = r % (2 * m1); int b = r / (2 * m1);
    int ky = (kyi < m1) ? kyi : (H - 2 * m1 + kyi);
    int tstep = (ky * stepH) & 255;
    const float2* base = Fx + ((size_t)(b * H) * m2 + kx) * Ct + c;
    size_t stride = (size_t)m2 * Ct;
    float accr = 0.f, acci = 0.f;
    int t = 0;
    for (int y = 0; y < H; y++) {
        float2 f = base[(size_t)y * stride];
        float cc = twc[t], ss = tws[t];
        accr += f.x * cc + f.y * ss;   // * e^{-i th}
        acci += f.y * cc - f.x * ss;
        t = (t + tstep) & 255;
    }
    XF[idx] = make_float2(accr, acci);
}

// Stage C: OF[(b*nmode+mode)*Co+o] = sum_i XF[(b*nmode+mode)*Ci+i] * w[i][o][ky][kx]
// Reads the ORIGINAL spectral weight layout [Ci,Co,m1,m2,2]; each weight
// element is read once, amortized over the 4 batches in registers.
__global__ void modemix2_kernel(const float2* __restrict__ XF,
                                const float* __restrict__ w1f, const float* __restrict__ w2f,
                                int Ci, int Co, int m1, int m2,
                                float2* __restrict__ OF) {
    __shared__ float2 xsm[4][224];
    int mode = blockIdx.x;
    int nmode = 2 * m1 * m2;
    for (int t = threadIdx.x; t < 4 * Ci; t += blockDim.x) {
        int b = t / Ci, i = t - b * Ci;
        xsm[b][i] = XF[((size_t)b * nmode + mode) * Ci + i];
    }
    __syncthreads();
    int o = threadIdx.x;
    if (o >= Co) return;
    int kx = mode % m2; int kyi = mode / m2;
    const float2* w = (const float2*)((kyi < m1) ? w1f : w2f);
    int ky = (kyi < m1) ? kyi : (kyi - m1);
    float ar0 = 0, ai0 = 0, ar1 = 0, ai1 = 0, ar2 = 0, ai2 = 0, ar3 = 0, ai3 = 0;
    for (int i = 0; i < Ci; i++) {
        float2 wv = w[(((size_t)i * Co + o) * m1 + ky) * m2 + kx];
        float2 a = xsm[0][i], b2 = xsm[1][i], c2 = xsm[2][i], d2 = xsm[3][i];
        ar0 += a.x * wv.x - a.y * wv.y;  ai0 += a.x * wv.y + a.y * wv.x;
        ar1 += b2.x * wv.x - b2.y * wv.y; ai1 += b2.x * wv.y + b2.y * wv.x;
        ar2 += c2.x * wv.x - c2.y * wv.y; ai2 += c2.x * wv.y + c2.y * wv.x;
        ar3 += d2.x * wv.x - d2.y * wv.y; ai3 += d2.x * wv.y + d2.y * wv.x;
    }
    OF[((size_t)0 * nmode + mode) * Co + o] = make_float2(ar0, ai0);
    OF[((size_t)1 * nmode + mode) * Co + o] = make_float2(ar1, ai1);
    OF[((size_t)2 * nmode + mode) * Co + o] = make_float2(ar2, ai2);
    OF[((size_t)3 * nmode + mode) * Co + o] = make_float2(ar3, ai3);
}

// Stage D: Gy[((b*H+y)*m2+kx)*Co+o] = sum_kyi OF[...] * e^{+2pi i ky y/H}
__global__ void idfty_kernel(const float2* __restrict__ OF, int H, int m1, int m2, int Co,
                             int stepH, const float2* __restrict__ tw,
                             float2* __restrict__ Gy, int N) {
    __shared__ float twc[256], tws[256];
    for (int t = threadIdx.x; t < 256; t += blockDim.x) {
        float2 v = tw[t]; twc[t] = v.x; tws[t] = v.y;
    }
    __syncthreads();
    int idx = blockIdx.x * blockDim.x + threadIdx.x;
    if (idx >= N) return;
    int o = idx % Co; int r = idx / Co;
    int kx = r % m2;  r /= m2;
    int y = r % H;    int b = r / H;
    float accr = 0.f, acci = 0.f;
    for (int kyi = 0; kyi < 2 * m1; kyi++) {
        int ky = (kyi < m1) ? kyi : (H - 2 * m1 + kyi);
        int t = (ky * y * stepH) & 255;
        float2 f = OF[((size_t)(b * 2 * m1 + kyi) * m2 + kx) * Co + o];
        float cc = twc[t], ss = tws[t];
        accr += f.x * cc - f.y * ss;   // * e^{+i th}
        acci += f.x * ss + f.y * cc;
    }
    Gy[idx] = make_float2(accr, acci);
}

// Stage E: out = gelu( invHW * halfspec_x_synth(Gy) + conv1x1([A|B]) + bias )
// SRCA: 0 direct, 1 lift-from-x, 2 bilinear-up. HEAD: fuse fc1+gelu+fc2
// (requires Co=64, P=4, block 256), writing [pix,3] to out.
template <int SRCA, bool HASB, bool HEAD>
__global__ void synth_kernel(const float2* __restrict__ Gy,
                             const float* __restrict__ A, int CA, int HsA, int WsA,
                             const float* __restrict__ UB, int CB,
                             const float* __restrict__ liftW, const float* __restrict__ liftB,
                             const float* __restrict__ WcT, const float* __restrict__ bias,
                             int H, int W, int Co, int P, int m2, int stepW, float invHW,
                             const float2* __restrict__ tw, float* __restrict__ out,
                             const float* __restrict__ fc1t, const float* __restrict__ fc1b,
                             const float* __restrict__ fc2w, const float* __restrict__ fc2b) {
    __shared__ float twc[256], tws[256];
    __shared__ float xs[4][224];
    __shared__ float hid[HEAD ? 4 * 256 : 4];
    int nthr = blockDim.x;
    int tid = threadIdx.x;
    for (int t = tid; t < 256; t += nthr) {
        float2 v = tw[t]; twc[t] = v.x; tws[t] = v.y;
    }
    int Ci = CA + (HASB ? CB : 0);
    int pix0 = blockIdx.x * P;
    for (int t = tid; t < P * Ci; t += nthr) {
        int p = t / Ci, i = t - p * Ci;
        int pix = pix0 + p;
        float val;
        if (HASB && i >= CA) {
            val = UB[(size_t)pix * CB + (i - CA)];
        } else if constexpr (SRCA == 0) {
            val = A[(size_t)pix * CA + i];
        } else if constexpr (SRCA == 1) {
            const float* xp = A + (size_t)pix * 6;
            float a = liftB[i];
#pragma unroll
            for (int j = 0; j < 6; j++) a += xp[j] * liftW[i * 6 + j];
            val = a;
        } else {
            int x = pix % W; int r = pix / W; int y = r % H; int b = r / H;
            float fy = 0.5f * y - 0.25f, fx = 0.5f * x - 0.25f;
            int y0 = (int)floorf(fy); float wy = fy - y0;
            int x0 = (int)floorf(fx); float wx = fx - x0;
            int ya = y0 < 0 ? 0 : y0;
            int yb = (y0 + 1 > HsA - 1) ? HsA - 1 : y0 + 1;
            int xa = x0 < 0 ? 0 : x0;
            int xb2 = (x0 + 1 > WsA - 1) ? WsA - 1 : x0 + 1;
            const float* base = A + ((size_t)b * HsA * WsA) * CA + i;
            float v00 = base[((size_t)ya * WsA + xa) * CA];
            float v01 = base[((size_t)ya * WsA + xb2) * CA];
            float v10 = base[((size_t)yb * WsA + xa) * CA];
            float v11 = base[((size_t)yb * WsA + xb2) * CA];
            val = (1.f - wy) * ((1.f - wx) * v00 + wx * v01) +
                  wy * ((1.f - wx) * v10 + wx * v11);
        }
        xs[p][i] = val;
    }
    __syncthreads();
    int o = tid % Co, p = tid / Co;     // blockDim == P*Co exactly
    int pix = pix0 + p;
    int x = pix % W; int by = pix / W;
    const float2* g = Gy + ((size_t)by * m2) * Co + o;
    int tstep = (x * stepW) & 255, t2 = 0;
    float acc = 0.f;
    for (int k = 0; k < m2; k++) {
        float2 gv = g[(size_t)k * Co];
        float v = gv.x * twc[t2] - gv.y * tws[t2];
        acc += (k == 0) ? v : 2.f * v;
        t2 = (t2 + tstep) & 255;
    }
    acc *= invHW;
    for (int i = 0; i < Ci; i++) acc += xs[p][i] * WcT[(size_t)i * Co + o];
    acc += bias[o];
    float gout = gelu_f(acc);
    if constexpr (!HEAD) {
        out[(size_t)pix * Co + o] = gout;
    } else {
        // Co==64, P==4, block 256
        __syncthreads();
        xs[p][o] = gout;               // stash 4x64 activations
        __syncthreads();
        int j = tid;                   // hidden unit 0..255
        float bb = fc1b[j];
#pragma unroll
        for (int pp = 0; pp < 4; pp++) {
            float a = bb;
            for (int i = 0; i < 64; i++) a += xs[pp][i] * fc1t[i * 256 + j];
            hid[pp * 256 + j] = gelu_f(a);
        }
        __syncthreads();
        if (tid < 12) {
            int pp = tid / 3, oo = tid - 3 * pp;
            float a = fc2b[oo];
            const float* wr = fc2w + oo * 256;
            const float* hr = hid + pp * 256;
            for (int i = 0; i < 256; i++) a += hr[i] * wr[i];
            out[(size_t)(pix0 + pp) * 3 + oo] = a;
        }
    }
}

// 2x2 mean pool; out dims [B,H2,W2,C]
__global__ void pool_kernel(const float* __restrict__ in, float* __restrict__ out,
                            int H2, int W2, int C, int N) {
    int idx = blockIdx.x * blockDim.x + threadIdx.x;
    if (idx >= N) return;
    int c = idx % C; int r = idx / C;
    int xo = r % W2; r /= W2;
    int yo = r % H2; int b = r / H2;
    int W = W2 * 2;
    const float* p = in + (((size_t)(b * (H2 * 2) + 2 * yo) * W) + 2 * xo) * C + c;
    float v = p[0] + p[C] + p[(size_t)W * C] + p[(size_t)W * C + C];
    out[idx] = 0.25f * v;
}

// ---------------------------------------------------------------------------

static inline unsigned nb_(size_t n, int b) { return (unsigned)((n + b - 1) / b); }

extern "C" void kernel_launch(void* const* d_in, const int* in_sizes, int n_in,
                              void* d_out, int out_size, void* d_ws, size_t ws_size,
                              hipStream_t stream) {
    (void)in_sizes; (void)n_in; (void)out_size;
    const float* x      = (const float*)d_in[0];
    const float* fcin_w = (const float*)d_in[1];
    const float* fcin_b = (const float*)d_in[2];
    const float* sc1_w1 = (const float*)d_in[3];
    const float* sc1_w2 = (const float*)d_in[4];
    const float* c1_w   = (const float*)d_in[5];
    const float* c1_b   = (const float*)d_in[6];
    const float* sc2_w1 = (const float*)d_in[7];
    const float* sc2_w2 = (const float*)d_in[8];
    const float* c2_w   = (const float*)d_in[9];
    const float* c2_b   = (const float*)d_in[10];
    const float* scb_w1 = (const float*)d_in[11];
    const float* scb_w2 = (const float*)d_in[12];
    const float* cb_w   = (const float*)d_in[13];
    const float* cb_b   = (const float*)d_in[14];
    const float* su2_w1 = (const float*)d_in[15];
    const float* su2_w2 = (const float*)d_in[16];
    const float* u2_w   = (const float*)d_in[17];
    const float* u2_b   = (const float*)d_in[18];
    const float* su1_w1 = (const float*)d_in[19];
    const float* su1_w2 = (const float*)d_in[20];
    const float* u1_w   = (const float*)d_in[21];
    const float* u1_b   = (const float*)d_in[22];
    const float* fc1_w  = (const float*)d_in[23];
    const float* fc1_b  = (const float*)d_in[24];
    const float* fc2_w  = (const float*)d_in[25];
    const float* fc2_b  = (const float*)d_in[26];
    float* out = (float*)d_out;

    float* wsf = (float*)d_ws;
    size_t off = 0;
    auto alloc = [&](size_t nfloats) -> float* {
        float* p = wsf + off;
        off += (nfloats + 63) & ~(size_t)63;
        return p;
    };

    float2* tw = (float2*)alloc(512);
    float* c1t  = alloc(64 * 64);
    float* c2t  = alloc(64 * 96);
    float* cbt  = alloc(96 * 128);
    float* u2t  = alloc(224 * 96);
    float* u1t  = alloc(160 * 64);
    float* fc1t = alloc(64 * 256);

    float* x1  = alloc((size_t)4 * 256 * 256 * 64);
    float* x1d = alloc((size_t)4 * 128 * 128 * 64);   // reused as x2d
    float* x2  = alloc((size_t)4 * 128 * 128 * 96);
    float* xb  = alloc((size_t)4 * 64 * 64 * 128);
    float* x2o = alloc((size_t)4 * 128 * 128 * 96);

    float2* Fx = (float2*)alloc((size_t)2 * 4 * 256 * 12 * 160);
    float2* XF = (float2*)alloc((size_t)2 * 4 * 24 * 12 * 160);
    float2* OF = (float2*)alloc((size_t)2 * 4 * 24 * 12 * 128);
    float2* Gy = (float2*)alloc((size_t)2 * 4 * 256 * 12 * 96);

    size_t need = off * sizeof(float);
    if (ws_size < need) {
        fprintf(stderr, "[FNO2d] workspace too small: need %zu bytes, have %zu\n",
                need, ws_size);
        return;
    }
    float* x2d = x1d;

    init_tw_kernel<<<1, 256, 0, stream>>>(tw);
    transpose_mat_kernel<<<nb_(64 * 64, 256), 256, 0, stream>>>(c1_w, c1t, 64, 64);
    transpose_mat_kernel<<<nb_(64 * 96, 256), 256, 0, stream>>>(c2_w, c2t, 96, 64);
    transpose_mat_kernel<<<nb_(96 * 128, 256), 256, 0, stream>>>(cb_w, cbt, 128, 96);
    transpose_mat_kernel<<<nb_(224 * 96, 256), 256, 0, stream>>>(u2_w, u2t, 96, 224);
    transpose_mat_kernel<<<nb_(160 * 64, 256), 256, 0, stream>>>(u1_w, u1t, 64, 160);
    transpose_mat_kernel<<<nb_(64 * 256, 256), 256, 0, stream>>>(fc1_w, fc1t, 256, 64);

    int N;

    // ---- L1: lift(x) -> 64ch, 256x256, m=12, Co=64 -> x1
    dftx_kernel<12, 1><<<dim3(1024, 1), 64, 0, stream>>>(
        x, 64, 0, 64, 256, 256, 0, 0, fcin_w, fcin_b, 1, tw, Fx);
    N = 4 * 24 * 12 * 64;
    dfty_kernel<<<nb_(N, 256), 256, 0, stream>>>(Fx, 256, 12, 12, 64, 1, tw, XF, N);
    modemix2_kernel<<<288, 128, 0, stream>>>(XF, sc1_w1, sc1_w2, 64, 64, 12, 12, OF);
    N = 4 * 256 * 12 * 64;
    idfty_kernel<<<nb_(N, 256), 256, 0, stream>>>(OF, 256, 12, 12, 64, 1, tw, Gy, N);
    synth_kernel<1, false, false><<<4 * 256 * 256 / 4, 256, 0, stream>>>(
        Gy, x, 64, 0, 0, nullptr, 0, fcin_w, fcin_b, c1t, c1_b,
        256, 256, 64, 4, 12, 1, 1.0f / 65536.0f, tw, x1,
        nullptr, nullptr, nullptr, nullptr);
    N = 4 * 128 * 128 * 64;
    pool_kernel<<<nb_(N, 256), 256, 0, stream>>>(x1, x1d, 128, 128, 64, N);

    // ---- L2: x1d 64ch, 128x128, m=8, Co=96 -> x2
    dftx_kernel<8, 0><<<dim3(512, 1), 64, 0, stream>>>(
        x1d, 64, 0, 64, 128, 128, 0, 0, nullptr, nullptr, 2, tw, Fx);
    N = 4 * 16 * 8 * 64;
    dfty_kernel<<<nb_(N, 256), 256, 0, stream>>>(Fx, 128, 8, 8, 64, 2, tw, XF, N);
    modemix2_kernel<<<128, 128, 0, stream>>>(XF, sc2_w1, sc2_w2, 64, 96, 8, 8, OF);
    N = 4 * 128 * 8 * 96;
    idfty_kernel<<<nb_(N, 256), 256, 0, stream>>>(OF, 128, 8, 8, 96, 2, tw, Gy, N);
    synth_kernel<0, false, false><<<4 * 128 * 128 / 2, 192, 0, stream>>>(
        Gy, x1d, 64, 0, 0, nullptr, 0, nullptr, nullptr, c2t, c2_b,
        128, 128, 96, 2, 8, 2, 1.0f / 16384.0f, tw, x2,
        nullptr, nullptr, nullptr, nullptr);
    N = 4 * 64 * 64 * 96;
    pool_kernel<<<nb_(N, 256), 256, 0, stream>>>(x2, x2d, 64, 64, 96, N);

    // ---- bottleneck: x2d 96ch, 64x64, m=4, Co=128 -> xb
    dftx_kernel<4, 0><<<dim3(256, 2), 64, 0, stream>>>(
        x2d, 96, 0, 96, 64, 64, 0, 0, nullptr, nullptr, 4, tw, Fx);
    N = 4 * 8 * 4 * 96;
    dfty_kernel<<<nb_(N, 256), 256, 0, stream>>>(Fx, 64, 4, 4, 96, 4, tw, XF, N);
    modemix2_kernel<<<32, 128, 0, stream>>>(XF, scb_w1, scb_w2, 96, 128, 4, 4, OF);
    N = 4 * 64 * 4 * 128;
    idfty_kernel<<<nb_(N, 256), 256, 0, stream>>>(OF, 64, 4, 4, 128, 4, tw, Gy, N);
    synth_kernel<0, false, false><<<4 * 64 * 64 / 2, 256, 0, stream>>>(
        Gy, x2d, 96, 0, 0, nullptr, 0, nullptr, nullptr, cbt, cb_b,
        64, 64, 128, 2, 4, 4, 1.0f / 4096.0f, tw, xb,
        nullptr, nullptr, nullptr, nullptr);

    // ---- U2: [up(xb) 128ch | x2 96ch], 128x128, m=8, Co=96 -> x2o
    dftx_kernel<8, 2><<<dim3(512, 2), 64, 0, stream>>>(
        xb, 128, 0, 224, 128, 128, 64, 64, nullptr, nullptr, 2, tw, Fx);
    dftx_kernel<8, 0><<<dim3(512, 2), 64, 0, stream>>>(
        x2, 96, 128, 224, 128, 128, 0, 0, nullptr, nullptr, 2, tw, Fx);
    N = 4 * 16 * 8 * 224;
    dfty_kernel<<<nb_(N, 256), 256, 0, stream>>>(Fx, 128, 8, 8, 224, 2, tw, XF, N);
    modemix2_kernel<<<128, 128, 0, stream>>>(XF, su2_w1, su2_w2, 224, 96, 8, 8, OF);
    N = 4 * 128 * 8 * 96;
    idfty_kernel<<<nb_(N, 256), 256, 0, stream>>>(OF, 128, 8, 8, 96, 2, tw, Gy, N);
    synth_kernel<2, true, false><<<4 * 128 * 128 / 2, 192, 0, stream>>>(
        Gy, xb, 128, 64, 64, x2, 96, nullptr, nullptr, u2t, u2_b,
        128, 128, 96, 2, 8, 2, 1.0f / 16384.0f, tw, x2o,
        nullptr, nullptr, nullptr, nullptr);

    // ---- U1: [up(x2o) 96ch | x1 64ch], 256x256, m=12, Co=64, + fused head -> out
    dftx_kernel<12, 2><<<dim3(1024, 2), 64, 0, stream>>>(
        x2o, 96, 0, 160, 256, 256, 128, 128, nullptr, nullptr, 1, tw, Fx);
    dftx_kernel<12, 0><<<dim3(1024, 1), 64, 0, stream>>>(
        x1, 64, 96, 160, 256, 256, 0, 0, nullptr, nullptr, 1, tw, Fx);
    N = 4 * 24 * 12 * 160;
    dfty_kernel<<<nb_(N, 256), 256, 0, stream>>>(Fx, 256, 12, 12, 160, 1, tw, XF, N);
    modemix2_kernel<<<288, 128, 0, stream>>>(XF, su1_w1, su1_w2, 160, 64, 12, 12, OF);
    N = 4 * 256 * 12 * 64;
    idfty_kernel<<<nb_(N, 256), 256, 0, stream>>>(OF, 256, 12, 12, 64, 1, tw, Gy, N);
    synth_kernel<2, true, true><<<4 * 256 * 256 / 4, 256, 0, stream>>>(
        Gy, x2o, 96, 128, 128, x1, 64, nullptr, nullptr, u1t, u1_b,
        256, 256, 64, 4, 12, 1, 1.0f / 65536.0f, tw, out,
        fc1t, fc1_b, fc2_w, fc2_b);
}

// Round 3
// 1773.269 us; speedup vs baseline: 2.1671x; 2.1671x over previous
//
#include <hip/hip_runtime.h>
#include <math.h>
#include <cstdio>

// ---------------------------------------------------------------------------
// FNO2d forward, MI355X. Channel-last f32 activations [B,H,W,C], B=4.
// Spectral conv via partial DFT (only m modes kept). Lift, bilinear
// upsampling, and the fc1/gelu/fc2 head are fused into the layer kernels.
// ---------------------------------------------------------------------------

__device__ __forceinline__ float gelu_f(float v) {
    return 0.5f * v * (1.0f + erff(v * 0.70710678118654752f));
}

// tw[t] = (cos(2*pi*t/256), sin(2*pi*t/256)); (k*x*step)&255 indexes
// e^{2*pi*i*k*x/N} for N in {64,128,256}, step = 256/N.
__global__ __launch_bounds__(256) void init_tw_kernel(float2* tw) {
    int t = threadIdx.x;
    tw[t] = make_float2(cospif(t * (1.0f / 128.0f)), sinpif(t * (1.0f / 128.0f)));
}

// [Co,Ci] -> dst[i*Co + o]
__global__ __launch_bounds__(256) void transpose_mat_kernel(const float* __restrict__ src,
                                                            float* __restrict__ dst,
                                                            int Co, int Ci) {
    int idx = blockIdx.x * blockDim.x + threadIdx.x;
    if (idx >= Ci * Co) return;
    int o = idx % Co; int i = idx / Co;
    dst[idx] = src[(size_t)o * Ci + i];
}

// Stage A: Fx[(by*M2+kx)*Ctot + Coff + c] = sum_x u(b,y,x,c) * e^{-2pi i kx x/W}
// SRC: 0 = direct [.,H,W,C]; 1 = lift from x[.,H,W,6]; 2 = bilinear-up from
// half-res S[.,Hs,Ws,C] (half-pixel centers, edge clamp).
template <int M2, int SRC>
__global__ __launch_bounds__(64, 4) void dftx_kernel(
    const float* __restrict__ U, int C, int Coff, int Ctot,
    int H, int W, int Hs, int Ws,
    const float* __restrict__ liftW, const float* __restrict__ liftB,
    int stepW, const float2* __restrict__ tw, float2* __restrict__ Fx) {
    __shared__ float twc[256], tws[256];
    for (int t = threadIdx.x; t < 256; t += blockDim.x) {
        float2 v = tw[t]; twc[t] = v.x; tws[t] = v.y;
    }
    __syncthreads();
    int by = blockIdx.x;                       // b*H + y
    int c = blockIdx.y * 64 + threadIdx.x;
    if (c >= C) return;

    const float* rowD = nullptr;
    const float* Sa = nullptr; const float* Sb = nullptr;
    float wy = 0.f, bc = 0.f;
    float w6[6] = {0, 0, 0, 0, 0, 0};
    if constexpr (SRC == 0) {
        rowD = U + (size_t)by * W * C + c;
    } else if constexpr (SRC == 1) {
        bc = liftB[c];
#pragma unroll
        for (int j = 0; j < 6; j++) w6[j] = liftW[c * 6 + j];
    } else {
        int b = by / H, y = by % H;
        float fy = 0.5f * y - 0.25f;
        int y0 = (int)floorf(fy); wy = fy - y0;
        int ya = y0 < 0 ? 0 : y0;
        int yb = (y0 + 1 > Hs - 1) ? Hs - 1 : y0 + 1;
        Sa = U + ((size_t)(b * Hs + ya) * Ws) * C + c;
        Sb = U + ((size_t)(b * Hs + yb) * Ws) * C + c;
    }

    float ar[M2], ai[M2];
#pragma unroll
    for (int k = 0; k < M2; k++) { ar[k] = 0.f; ai[k] = 0.f; }
    for (int x = 0; x < W; x++) {
        float u;
        if constexpr (SRC == 0) {
            u = rowD[(size_t)x * C];
        } else if constexpr (SRC == 1) {
            const float* xp = U + ((size_t)by * W + x) * 6;
            u = bc;
#pragma unroll
            for (int j = 0; j < 6; j++) u += w6[j] * xp[j];
        } else {
            float fx = 0.5f * x - 0.25f;
            int x0 = (int)floorf(fx); float wx = fx - x0;
            int xa = x0 < 0 ? 0 : x0;
            int xb2 = (x0 + 1 > Ws - 1) ? Ws - 1 : x0 + 1;
            float va = Sa[(size_t)xa * C] * (1.f - wx) + Sa[(size_t)xb2 * C] * wx;
            float vb = Sb[(size_t)xa * C] * (1.f - wx) + Sb[(size_t)xb2 * C] * wx;
            u = va * (1.f - wy) + vb * wy;
        }
        int tb = (x * stepW) & 255;
        int t = 0;
#pragma unroll
        for (int k = 0; k < M2; k++) {
            ar[k] += u * twc[t];
            ai[k] -= u * tws[t];
            t = (t + tb) & 255;
        }
    }
    float2* o = Fx + ((size_t)by * M2) * Ctot + Coff + c;
#pragma unroll
    for (int k = 0; k < M2; k++) o[(size_t)k * Ctot] = make_float2(ar[k], ai[k]);
}

// Stage B: XF[((b*2m1+kyi)*m2+kx)*Ct + c] = sum_y Fx[...] * e^{-2pi i ky y/H}
__global__ __launch_bounds__(256, 4) void dfty_kernel(
    const float2* __restrict__ Fx, int H, int m1, int m2, int Ct,
    int stepH, const float2* __restrict__ tw, float2* __restrict__ XF, int N) {
    __shared__ float twc[256], tws[256];
    for (int t = threadIdx.x; t < 256; t += blockDim.x) {
        float2 v = tw[t]; twc[t] = v.x; tws[t] = v.y;
    }
    __syncthreads();
    int idx = blockIdx.x * blockDim.x + threadIdx.x;
    if (idx >= N) return;
    int c = idx % Ct; int r = idx / Ct;
    int kx = r % m2;  r /= m2;
    int kyi = r % (2 * m1); int b = r / (2 * m1);
    int ky = (kyi < m1) ? kyi : (H - 2 * m1 + kyi);
    int tstep = (ky * stepH) & 255;
    const float2* base = Fx + ((size_t)(b * H) * m2 + kx) * Ct + c;
    size_t stride = (size_t)m2 * Ct;
    float accr = 0.f, acci = 0.f;
    int t = 0;
    for (int y = 0; y < H; y++) {
        float2 f = base[(size_t)y * stride];
        float cc = twc[t], ss = tws[t];
        accr += f.x * cc + f.y * ss;   // * e^{-i th}
        acci += f.y * cc - f.x * ss;
        t = (t + tstep) & 255;
    }
    XF[idx] = make_float2(accr, acci);
}

// Stage C: OF[(b*nmode+mode)*Co+o] = sum_i XF[(b*nmode+mode)*Ci+i] * w[i][o][ky][kx]
// Reads the ORIGINAL spectral weight layout [Ci,Co,m1,m2,2]; each weight
// element is read once, amortized over the 4 batches in registers.
__global__ __launch_bounds__(128, 2) void modemix2_kernel(
    const float2* __restrict__ XF,
    const float* __restrict__ w1f, const float* __restrict__ w2f,
    int Ci, int Co, int m1, int m2, float2* __restrict__ OF) {
    __shared__ float2 xsm[4][224];
    int mode = blockIdx.x;
    int nmode = 2 * m1 * m2;
    for (int t = threadIdx.x; t < 4 * Ci; t += blockDim.x) {
        int b = t / Ci, i = t - b * Ci;
        xsm[b][i] = XF[((size_t)b * nmode + mode) * Ci + i];
    }
    __syncthreads();
    int o = threadIdx.x;
    if (o >= Co) return;
    int kx = mode % m2; int kyi = mode / m2;
    const float2* w = (const float2*)((kyi < m1) ? w1f : w2f);
    int ky = (kyi < m1) ? kyi : (kyi - m1);
    float ar0 = 0, ai0 = 0, ar1 = 0, ai1 = 0, ar2 = 0, ai2 = 0, ar3 = 0, ai3 = 0;
    for (int i = 0; i < Ci; i++) {
        float2 wv = w[(((size_t)i * Co + o) * m1 + ky) * m2 + kx];
        float2 a = xsm[0][i], b2 = xsm[1][i], c2 = xsm[2][i], d2 = xsm[3][i];
        ar0 += a.x * wv.x - a.y * wv.y;  ai0 += a.x * wv.y + a.y * wv.x;
        ar1 += b2.x * wv.x - b2.y * wv.y; ai1 += b2.x * wv.y + b2.y * wv.x;
        ar2 += c2.x * wv.x - c2.y * wv.y; ai2 += c2.x * wv.y + c2.y * wv.x;
        ar3 += d2.x * wv.x - d2.y * wv.y; ai3 += d2.x * wv.y + d2.y * wv.x;
    }
    OF[((size_t)0 * nmode + mode) * Co + o] = make_float2(ar0, ai0);
    OF[((size_t)1 * nmode + mode) * Co + o] = make_float2(ar1, ai1);
    OF[((size_t)2 * nmode + mode) * Co + o] = make_float2(ar2, ai2);
    OF[((size_t)3 * nmode + mode) * Co + o] = make_float2(ar3, ai3);
}

// Stage D: Gy[((b*H+y)*m2+kx)*Co+o] = sum_kyi OF[...] * e^{+2pi i ky y/H}
__global__ __launch_bounds__(256, 4) void idfty_kernel(
    const float2* __restrict__ OF, int H, int m1, int m2, int Co,
    int stepH, const float2* __restrict__ tw, float2* __restrict__ Gy, int N) {
    __shared__ float twc[256], tws[256];
    for (int t = threadIdx.x; t < 256; t += blockDim.x) {
        float2 v = tw[t]; twc[t] = v.x; tws[t] = v.y;
    }
    __syncthreads();
    int idx = blockIdx.x * blockDim.x + threadIdx.x;
    if (idx >= N) return;
    int o = idx % Co; int r = idx / Co;
    int kx = r % m2;  r /= m2;
    int y = r % H;    int b = r / H;
    float accr = 0.f, acci = 0.f;
    for (int kyi = 0; kyi < 2 * m1; kyi++) {
        int ky = (kyi < m1) ? kyi : (H - 2 * m1 + kyi);
        int t = (ky * y * stepH) & 255;
        float2 f = OF[((size_t)(b * 2 * m1 + kyi) * m2 + kx) * Co + o];
        float cc = twc[t], ss = tws[t];
        accr += f.x * cc - f.y * ss;   // * e^{+i th}
        acci += f.x * ss + f.y * cc;
    }
    Gy[idx] = make_float2(accr, acci);
}

// Stage E: out = gelu( invHW * halfspec_x_synth(Gy) + conv1x1([A|B]) + bias )
// Block = CO*G threads; owns P = G*PPG consecutive pixels of ONE image row.
// Thread (o = tid%CO, g = tid/CO) computes PPG pixels, so each weight load
// is amortized over PPG FMAs. HEAD additionally fuses fc1+gelu+fc2 (CO=64,
// P=16, block 256), writing [pix,3] to out.
template <int SRCA, bool HASB, bool HEAD, int CO, int G, int PPG, int CIMAX>
__global__ __launch_bounds__(CO * G, 2) void synth_kernel(
    const float2* __restrict__ Gy,
    const float* __restrict__ A, int CA, int HsA, int WsA,
    const float* __restrict__ UB, int CB,
    const float* __restrict__ liftW, const float* __restrict__ liftB,
    const float* __restrict__ WcT, const float* __restrict__ bias,
    int H, int W, int m2, int stepW, float invHW,
    const float2* __restrict__ tw, float* __restrict__ out,
    const float* __restrict__ fc1t, const float* __restrict__ fc1b,
    const float* __restrict__ fc2w, const float* __restrict__ fc2b) {
    constexpr int P = G * PPG;
    constexpr int BLK = CO * G;
    __shared__ float twc[256], tws[256];
    __shared__ float xs[P][CIMAX];
    __shared__ float hid[HEAD ? P * 256 : 1];
    int tid = threadIdx.x;
    for (int t = tid; t < 256; t += BLK) {
        float2 v = tw[t]; twc[t] = v.x; tws[t] = v.y;
    }
    const int Ci = CA + (HASB ? CB : 0);
    int pix0 = blockIdx.x * P;
    for (int t = tid; t < P * Ci; t += BLK) {
        int p = t / Ci, i = t - p * Ci;
        int pix = pix0 + p;
        float val;
        if (HASB && i >= CA) {
            val = UB[(size_t)pix * CB + (i - CA)];
        } else if constexpr (SRCA == 0) {
            val = A[(size_t)pix * CA + i];
        } else if constexpr (SRCA == 1) {
            const float* xp = A + (size_t)pix * 6;
            float a = liftB[i];
#pragma unroll
            for (int j = 0; j < 6; j++) a += xp[j] * liftW[i * 6 + j];
            val = a;
        } else {
            int x = pix % W; int r = pix / W; int y = r % H; int b = r / H;
            float fy = 0.5f * y - 0.25f, fx = 0.5f * x - 0.25f;
            int y0 = (int)floorf(fy); float wy = fy - y0;
            int x0 = (int)floorf(fx); float wx = fx - x0;
            int ya = y0 < 0 ? 0 : y0;
            int yb = (y0 + 1 > HsA - 1) ? HsA - 1 : y0 + 1;
            int xa = x0 < 0 ? 0 : x0;
            int xb2 = (x0 + 1 > WsA - 1) ? WsA - 1 : x0 + 1;
            const float* base = A + ((size_t)b * HsA * WsA) * CA + i;
            float v00 = base[((size_t)ya * WsA + xa) * CA];
            float v01 = base[((size_t)ya * WsA + xb2) * CA];
            float v10 = base[((size_t)yb * WsA + xa) * CA];
            float v11 = base[((size_t)yb * WsA + xb2) * CA];
            val = (1.f - wy) * ((1.f - wx) * v00 + wx * v01) +
                  wy * ((1.f - wx) * v10 + wx * v11);
        }
        xs[p][i] = val;
    }
    __syncthreads();
    int o = tid % CO, g = tid / CO;
    int x0 = pix0 % W;  int by = pix0 / W;     // all P pixels share one row
    int xg = x0 + g * PPG;
    float acc[PPG];
#pragma unroll
    for (int q = 0; q < PPG; q++) acc[q] = 0.f;
    const float2* grow = Gy + ((size_t)by * m2) * CO + o;
    int base = (xg * stepW) & 255;
    for (int k = 0; k < m2; k++) {
        float2 gv = grow[(size_t)k * CO];
        float sc = (k == 0) ? 1.f : 2.f;
        float gx = sc * gv.x, gyv = sc * gv.y;
        int dk = (k * stepW) & 255;
        int t = (base * k) & 255;
#pragma unroll
        for (int q = 0; q < PPG; q++) {
            acc[q] += gx * twc[t] - gyv * tws[t];
            t = (t + dk) & 255;
        }
    }
#pragma unroll
    for (int q = 0; q < PPG; q++) acc[q] *= invHW;
    for (int i = 0; i < Ci; i++) {
        float w = WcT[(size_t)i * CO + o];
#pragma unroll
        for (int q = 0; q < PPG; q++) acc[q] += xs[g * PPG + q][i] * w;
    }
    float bb = bias[o];
    if constexpr (!HEAD) {
#pragma unroll
        for (int q = 0; q < PPG; q++) {
            int pix = pix0 + g * PPG + q;
            out[(size_t)pix * CO + o] = gelu_f(acc[q] + bb);
        }
    } else {
        // CO==64, P==16, BLK==256. Activations overlay xs.
        float gout[PPG];
#pragma unroll
        for (int q = 0; q < PPG; q++) gout[q] = gelu_f(acc[q] + bb);
        __syncthreads();                       // conv reads of xs are done
        float* act = &xs[0][0];                // act[p*64 + o]
#pragma unroll
        for (int q = 0; q < PPG; q++) act[(g * PPG + q) * 64 + o] = gout[q];
        __syncthreads();
        int j = tid;                           // hidden unit 0..255
        float h[P];
        float c1 = fc1b[j];
#pragma unroll
        for (int p = 0; p < P; p++) h[p] = c1;
        for (int i = 0; i < 64; i++) {
            float w = fc1t[i * 256 + j];
#pragma unroll
            for (int p = 0; p < P; p++) h[p] += act[p * 64 + i] * w;
        }
#pragma unroll
        for (int p = 0; p < P; p++) hid[p * 256 + j] = gelu_f(h[p]);
        __syncthreads();
        // fc2: 4 lanes per (pixel, out3) dot of length 256
        if (tid < P * 12) {
            int sub = tid & 3; int d = tid >> 2;    // d < 48
            int o3 = d % 3, p = d / 3;
            const float* hr = hid + p * 256;
            const float* wr = fc2w + o3 * 256;
            float a = 0.f;
            for (int i = sub; i < 256; i += 4) a += hr[i] * wr[i];
            a += __shfl_xor(a, 1);
            a += __shfl_xor(a, 2);
            if (sub == 0) out[(size_t)(pix0 + p) * 3 + o3] = a + fc2b[o3];
        }
    }
}

// 2x2 mean pool; out dims [B,H2,W2,C]
__global__ __launch_bounds__(256, 4) void pool_kernel(
    const float* __restrict__ in, float* __restrict__ out,
    int H2, int W2, int C, int N) {
    int idx = blockIdx.x * blockDim.x + threadIdx.x;
    if (idx >= N) return;
    int c = idx % C; int r = idx / C;
    int xo = r % W2; r /= W2;
    int yo = r % H2; int b = r / H2;
    int W = W2 * 2;
    const float* p = in + (((size_t)(b * (H2 * 2) + 2 * yo) * W) + 2 * xo) * C + c;
    float v = p[0] + p[C] + p[(size_t)W * C] + p[(size_t)W * C + C];
    out[idx] = 0.25f * v;
}

// ---------------------------------------------------------------------------

static inline unsigned nb_(size_t n, int b) { return (unsigned)((n + b - 1) / b); }

extern "C" void kernel_launch(void* const* d_in, const int* in_sizes, int n_in,
                              void* d_out, int out_size, void* d_ws, size_t ws_size,
                              hipStream_t stream) {
    (void)in_sizes; (void)n_in; (void)out_size;
    const float* x      = (const float*)d_in[0];
    const float* fcin_w = (const float*)d_in[1];
    const float* fcin_b = (const float*)d_in[2];
    const float* sc1_w1 = (const float*)d_in[3];
    const float* sc1_w2 = (const float*)d_in[4];
    const float* c1_w   = (const float*)d_in[5];
    const float* c1_b   = (const float*)d_in[6];
    const float* sc2_w1 = (const float*)d_in[7];
    const float* sc2_w2 = (const float*)d_in[8];
    const float* c2_w   = (const float*)d_in[9];
    const float* c2_b   = (const float*)d_in[10];
    const float* scb_w1 = (const float*)d_in[11];
    const float* scb_w2 = (const float*)d_in[12];
    const float* cb_w   = (const float*)d_in[13];
    const float* cb_b   = (const float*)d_in[14];
    const float* su2_w1 = (const float*)d_in[15];
    const float* su2_w2 = (const float*)d_in[16];
    const float* u2_w   = (const float*)d_in[17];
    const float* u2_b   = (const float*)d_in[18];
    const float* su1_w1 = (const float*)d_in[19];
    const float* su1_w2 = (const float*)d_in[20];
    const float* u1_w   = (const float*)d_in[21];
    const float* u1_b   = (const float*)d_in[22];
    const float* fc1_w  = (const float*)d_in[23];
    const float* fc1_b  = (const float*)d_in[24];
    const float* fc2_w  = (const float*)d_in[25];
    const float* fc2_b  = (const float*)d_in[26];
    float* out = (float*)d_out;

    float* wsf = (float*)d_ws;
    size_t off = 0;
    auto alloc = [&](size_t nfloats) -> float* {
        float* p = wsf + off;
        off += (nfloats + 63) & ~(size_t)63;
        return p;
    };

    float2* tw = (float2*)alloc(512);
    float* c1t  = alloc(64 * 64);
    float* c2t  = alloc(64 * 96);
    float* cbt  = alloc(96 * 128);
    float* u2t  = alloc(224 * 96);
    float* u1t  = alloc(160 * 64);
    float* fc1t = alloc(64 * 256);

    float* x1  = alloc((size_t)4 * 256 * 256 * 64);
    float* x1d = alloc((size_t)4 * 128 * 128 * 64);   // reused as x2d
    float* x2  = alloc((size_t)4 * 128 * 128 * 96);
    float* xb  = alloc((size_t)4 * 64 * 64 * 128);
    float* x2o = alloc((size_t)4 * 128 * 128 * 96);

    float2* Fx = (float2*)alloc((size_t)2 * 4 * 256 * 12 * 160);
    float2* XF = (float2*)alloc((size_t)2 * 4 * 24 * 12 * 160);
    float2* OF = (float2*)alloc((size_t)2 * 4 * 24 * 12 * 128);
    float2* Gy = (float2*)alloc((size_t)2 * 4 * 256 * 12 * 96);

    size_t need = off * sizeof(float);
    if (ws_size < need) {
        fprintf(stderr, "[FNO2d] workspace too small: need %zu bytes, have %zu\n",
                need, ws_size);
        return;
    }
    float* x2d = x1d;

    init_tw_kernel<<<1, 256, 0, stream>>>(tw);
    transpose_mat_kernel<<<nb_(64 * 64, 256), 256, 0, stream>>>(c1_w, c1t, 64, 64);
    transpose_mat_kernel<<<nb_(64 * 96, 256), 256, 0, stream>>>(c2_w, c2t, 96, 64);
    transpose_mat_kernel<<<nb_(96 * 128, 256), 256, 0, stream>>>(cb_w, cbt, 128, 96);
    transpose_mat_kernel<<<nb_(224 * 96, 256), 256, 0, stream>>>(u2_w, u2t, 96, 224);
    transpose_mat_kernel<<<nb_(160 * 64, 256), 256, 0, stream>>>(u1_w, u1t, 64, 160);
    transpose_mat_kernel<<<nb_(64 * 256, 256), 256, 0, stream>>>(fc1_w, fc1t, 256, 64);

    int N;

    // ---- L1: lift(x) -> 64ch, 256x256, m=12, Co=64 -> x1
    dftx_kernel<12, 1><<<dim3(1024, 1), 64, 0, stream>>>(
        x, 64, 0, 64, 256, 256, 0, 0, fcin_w, fcin_b, 1, tw, Fx);
    N = 4 * 24 * 12 * 64;
    dfty_kernel<<<nb_(N, 256), 256, 0, stream>>>(Fx, 256, 12, 12, 64, 1, tw, XF, N);
    modemix2_kernel<<<288, 128, 0, stream>>>(XF, sc1_w1, sc1_w2, 64, 64, 12, 12, OF);
    N = 4 * 256 * 12 * 64;
    idfty_kernel<<<nb_(N, 256), 256, 0, stream>>>(OF, 256, 12, 12, 64, 1, tw, Gy, N);
    synth_kernel<1, false, false, 64, 4, 4, 64><<<4 * 256 * 256 / 16, 256, 0, stream>>>(
        Gy, x, 64, 0, 0, nullptr, 0, fcin_w, fcin_b, c1t, c1_b,
        256, 256, 12, 1, 1.0f / 65536.0f, tw, x1,
        nullptr, nullptr, nullptr, nullptr);
    N = 4 * 128 * 128 * 64;
    pool_kernel<<<nb_(N, 256), 256, 0, stream>>>(x1, x1d, 128, 128, 64, N);

    // ---- L2: x1d 64ch, 128x128, m=8, Co=96 -> x2
    dftx_kernel<8, 0><<<dim3(512, 1), 64, 0, stream>>>(
        x1d, 64, 0, 64, 128, 128, 0, 0, nullptr, nullptr, 2, tw, Fx);
    N = 4 * 16 * 8 * 64;
    dfty_kernel<<<nb_(N, 256), 256, 0, stream>>>(Fx, 128, 8, 8, 64, 2, tw, XF, N);
    modemix2_kernel<<<128, 128, 0, stream>>>(XF, sc2_w1, sc2_w2, 64, 96, 8, 8, OF);
    N = 4 * 128 * 8 * 96;
    idfty_kernel<<<nb_(N, 256), 256, 0, stream>>>(OF, 128, 8, 8, 96, 2, tw, Gy, N);
    synth_kernel<0, false, false, 96, 2, 4, 64><<<4 * 128 * 128 / 8, 192, 0, stream>>>(
        Gy, x1d, 64, 0, 0, nullptr, 0, nullptr, nullptr, c2t, c2_b,
        128, 128, 8, 2, 1.0f / 16384.0f, tw, x2,
        nullptr, nullptr, nullptr, nullptr);
    N = 4 * 64 * 64 * 96;
    pool_kernel<<<nb_(N, 256), 256, 0, stream>>>(x2, x2d, 64, 64, 96, N);

    // ---- bottleneck: x2d 96ch, 64x64, m=4, Co=128 -> xb
    dftx_kernel<4, 0><<<dim3(256, 2), 64, 0, stream>>>(
        x2d, 96, 0, 96, 64, 64, 0, 0, nullptr, nullptr, 4, tw, Fx);
    N = 4 * 8 * 4 * 96;
    dfty_kernel<<<nb_(N, 256), 256, 0, stream>>>(Fx, 64, 4, 4, 96, 4, tw, XF, N);
    modemix2_kernel<<<32, 128, 0, stream>>>(XF, scb_w1, scb_w2, 96, 128, 4, 4, OF);
    N = 4 * 64 * 4 * 128;
    idfty_kernel<<<nb_(N, 256), 256, 0, stream>>>(OF, 64, 4, 4, 128, 4, tw, Gy, N);
    synth_kernel<0, false, false, 128, 2, 4, 96><<<4 * 64 * 64 / 8, 256, 0, stream>>>(
        Gy, x2d, 96, 0, 0, nullptr, 0, nullptr, nullptr, cbt, cb_b,
        64, 64, 4, 4, 1.0f / 4096.0f, tw, xb,
        nullptr, nullptr, nullptr, nullptr);

    // ---- U2: [up(xb) 128ch | x2 96ch], 128x128, m=8, Co=96 -> x2o
    dftx_kernel<8, 2><<<dim3(512, 2), 64, 0, stream>>>(
        xb, 128, 0, 224, 128, 128, 64, 64, nullptr, nullptr, 2, tw, Fx);
    dftx_kernel<8, 0><<<dim3(512, 2), 64, 0, stream>>>(
        x2, 96, 128, 224, 128, 128, 0, 0, nullptr, nullptr, 2, tw, Fx);
    N = 4 * 16 * 8 * 224;
    dfty_kernel<<<nb_(N, 256), 256, 0, stream>>>(Fx, 128, 8, 8, 224, 2, tw, XF, N);
    modemix2_kernel<<<128, 128, 0, stream>>>(XF, su2_w1, su2_w2, 224, 96, 8, 8, OF);
    N = 4 * 128 * 8 * 96;
    idfty_kernel<<<nb_(N, 256), 256, 0, stream>>>(OF, 128, 8, 8, 96, 2, tw, Gy, N);
    synth_kernel<2, true, false, 96, 2, 4, 224><<<4 * 128 * 128 / 8, 192, 0, stream>>>(
        Gy, xb, 128, 64, 64, x2, 96, nullptr, nullptr, u2t, u2_b,
        128, 128, 8, 2, 1.0f / 16384.0f, tw, x2o,
        nullptr, nullptr, nullptr, nullptr);

    // ---- U1: [up(x2o) 96ch | x1 64ch], 256x256, m=12, Co=64, + fused head -> out
    dftx_kernel<12, 2><<<dim3(1024, 2), 64, 0, stream>>>(
        x2o, 96, 0, 160, 256, 256, 128, 128, nullptr, nullptr, 1, tw, Fx);
    dftx_kernel<12, 0><<<dim3(1024, 1), 64, 0, stream>>>(
        x1, 64, 96, 160, 256, 256, 0, 0, nullptr, nullptr, 1, tw, Fx);
    N = 4 * 24 * 12 * 160;
    dfty_kernel<<<nb_(N, 256), 256, 0, stream>>>(Fx, 256, 12, 12, 160, 1, tw, XF, N);
    modemix2_kernel<<<288, 128, 0, stream>>>(XF, su1_w1, su1_w2, 160, 64, 12, 12, OF);
    N = 4 * 256 * 12 * 64;
    idfty_kernel<<<nb_(N, 256), 256, 0, stream>>>(OF, 256, 12, 12, 64, 1, tw, Gy, N);
    synth_kernel<2, true, true, 64, 4, 4, 160><<<4 * 256 * 256 / 16, 256, 0, stream>>>(
        Gy, x2o, 96, 128, 128, x1, 64, nullptr, nullptr, u1t, u1_b,
        256, 256, 12, 1, 1.0f / 65536.0f, tw, out,
        fc1t, fc1_b, fc2_w, fc2_b);
}